// Round 5
// baseline (38.115 us; speedup 1.0000x reference)
//
#include <hip/hip_runtime.h>

// Denoiser MLP (2->16, 5x 16->16, 16->2), fp32 in/out, via fp16 MFMA.
// R5: latency-chain attack.
//  - software prefetch: next chunk's x loaded before current chunk's compute
//    (HBM latency hides under ~400 cyc of MFMA+VALU work)
//  - input layer moved onto MFMA: A = W_in zero-padded to 16x16 (cols k>=2
//    zero), so B-operand garbage in k>=2 is annihilated -> B build is just
//    cvt_pkrtz(x.x,x.y) packed low, no lane masking at all
//  - ReLU as one h4 elementwise_max (2x v_pk_max_f16)
//
// MFMA layout (16x16x16 f16, D=W*g with activations transposed):
//   A frag: lane holds A[i=lane&15][k=4*(lane>>4)+j]
//   B frag: lane holds B[k=4*(lane>>4)+j][n=lane&15]
//   D frag: lane holds D[i=4*(lane>>4)+r][n=lane&15]
// D layout == B layout -> layer chaining with zero cross-lane traffic.

typedef _Float16 h4 __attribute__((ext_vector_type(4)));
typedef _Float16 h2 __attribute__((ext_vector_type(2)));
typedef float f4 __attribute__((ext_vector_type(4)));
typedef float f2 __attribute__((ext_vector_type(2)));
typedef unsigned int u32;
typedef u32 u2v __attribute__((ext_vector_type(2)));

static __device__ __forceinline__ f4 mfma16(h4 a, h4 b, f4 c) {
    return __builtin_amdgcn_mfma_f32_16x16x16f16(a, b, c, 0, 0, 0);
}

static __device__ __forceinline__ h4 pack2(u32 lo, u32 hi) {
    u2v p = {lo, hi};
    return __builtin_bit_cast(h4, p);
}

static __device__ __forceinline__ u32 cvtpk(float a, float b) {
    return __builtin_bit_cast(u32, __builtin_amdgcn_cvt_pkrtz(a, b));
}

static __device__ __forceinline__ h4 cvt_relu(f4 v) {
    h4 hb = pack2(cvtpk(v.x, v.y), cvtpk(v.z, v.w));
    const h4 z = {(_Float16)0.f, (_Float16)0.f, (_Float16)0.f, (_Float16)0.f};
    return __builtin_elementwise_max(hb, z);   // 2x v_pk_max_f16
}

__global__ __launch_bounds__(256) void denoiser_mfma(
    const f2* __restrict__ x,        // [N] points (x0,x1)
    const float* __restrict__ w_in,  // [16][2]
    const float* __restrict__ w_mid, // [5][16][16]
    const float* __restrict__ w_out, // [2][16]
    f2* __restrict__ out,            // [N] (o0,o1)
    int n)
{
    const int lane = threadIdx.x & 63;
    const int m    = lane & 15;   // point-in-tile / A-row index
    const int g    = lane >> 4;   // k-group
    const int wave = threadIdx.x >> 6;

    const f4 zero = (f4){0.f, 0.f, 0.f, 0.f};
    const h4 hz   = (h4){(_Float16)0.f, (_Float16)0.f, (_Float16)0.f, (_Float16)0.f};

    // ---- one-time weight fragments ----
    // input layer: A[i=m][k] = w_in[m][k] for k<2, else 0  (only g==0 lanes)
    h4 wi = hz;
    if (g == 0) {
        f2 w = ((const f2*)w_in)[m];
        wi = pack2(cvtpk(w.x, w.y), 0u);
    }
    // mid layers
    h4 wm[5];
    #pragma unroll
    for (int l = 0; l < 5; ++l) {
        f4 v = *(const f4*)(w_mid + l * 256 + m * 16 + 4 * g);
        wm[l] = pack2(cvtpk(v.x, v.y), cvtpk(v.z, v.w));
    }
    // output layer: rows 0,1 real, rest zero
    h4 wo = hz;
    if (m < 2) {
        f4 v = *(const f4*)(w_out + m * 16 + 4 * g);
        wo = pack2(cvtpk(v.x, v.y), cvtpk(v.z, v.w));
    }

    const int nchunks = (n + 255) >> 8;     // 256 points per block-chunk
    const int stride  = gridDim.x;

    int c = blockIdx.x;
    f2 xy[4];
    if (c < nchunks) {
        int b0 = c * 256 + wave * 64;
        #pragma unroll
        for (int t = 0; t < 4; ++t) {
            int pi = b0 + t * 16 + m;
            xy[t] = x[pi < n ? pi : n - 1];
        }
    }

    for (; c < nchunks; c += stride) {
        // ---- prefetch next chunk's x (hides HBM latency under compute) ----
        const int cn = c + stride;
        f2 xyn[4];
        if (cn < nchunks) {
            int b0 = cn * 256 + wave * 64;
            #pragma unroll
            for (int t = 0; t < 4; ++t) {
                int pi = b0 + t * 16 + m;
                xyn[t] = x[pi < n ? pi : n - 1];
            }
        }

        // ---- input layer as MFMA: B = {x.x, x.y, *, *}; A kills k>=2 ----
        h4 b[4];
        f4 acc[4];
        #pragma unroll
        for (int t = 0; t < 4; ++t)
            b[t] = pack2(cvtpk(xy[t].x, xy[t].y), 0u);
        #pragma unroll
        for (int t = 0; t < 4; ++t)
            acc[t] = mfma16(wi, b[t], zero);
        #pragma unroll
        for (int t = 0; t < 4; ++t)
            b[t] = cvt_relu(acc[t]);

        // ---- 5 mid layers ----
        #pragma unroll
        for (int l = 0; l < 5; ++l) {
            #pragma unroll
            for (int t = 0; t < 4; ++t)
                acc[t] = mfma16(wm[l], b[t], zero);
            #pragma unroll
            for (int t = 0; t < 4; ++t)
                b[t] = cvt_relu(acc[t]);
        }

        // ---- output layer ----
        #pragma unroll
        for (int t = 0; t < 4; ++t)
            acc[t] = mfma16(wo, b[t], zero);

        const int base = c * 256 + wave * 64;
        if (g == 0) {
            if (base + 64 <= n) {
                #pragma unroll
                for (int t = 0; t < 4; ++t)
                    out[base + t * 16 + m] = (f2){acc[t].x, acc[t].y};
            } else {
                #pragma unroll
                for (int t = 0; t < 4; ++t) {
                    int pi = base + t * 16 + m;
                    if (pi < n) out[pi] = (f2){acc[t].x, acc[t].y};
                }
            }
        }

        #pragma unroll
        for (int t = 0; t < 4; ++t) xy[t] = xyn[t];
    }
}

extern "C" void kernel_launch(void* const* d_in, const int* in_sizes, int n_in,
                              void* d_out, int out_size, void* d_ws, size_t ws_size,
                              hipStream_t stream) {
    const float* x     = (const float*)d_in[0];
    const float* w_in  = (const float*)d_in[1];
    const float* w_mid = (const float*)d_in[2];
    const float* w_out = (const float*)d_in[3];

    int n = in_sizes[0] / 2;          // number of points
    int nchunks = (n + 255) / 256;
    int blocks = nchunks < 2048 ? nchunks : 2048;  // 8 blocks/CU persistent

    denoiser_mfma<<<blocks, 256, 0, stream>>>(
        (const f2*)x, w_in, w_mid, w_out, (f2*)d_out, n);
}

// Round 6
// 37.966 us; speedup vs baseline: 1.0039x; 1.0039x over previous
//
#include <hip/hip_runtime.h>

// Denoiser MLP (2->16, 5x 16->16, 16->2), fp32 in/out, via gfx950-native
// v_mfma_f32_32x32x16_f16 (legacy 16x16x16 measured ~57 cyc/SIMD in R5 -> slow).
//
// Mapping: activations transposed (features x points), D = A*B per layer:
//   A (32x16) = [W; W]  (16x16 weights, rows duplicated)
//   B (16x32) = 32 points' features
//   A frag: lane l holds A[i=l&31][k=8*(l>>5)+j], j=0..7
//   B frag: lane l holds B[k=8*(l>>5)+j][n=l&31]
//   D frag: lane l holds D[i=(reg&3)+8*(reg>>2)+4*(l>>5)][n=l&31], reg 0..15
// D regs 0-7 at hi=l>>5 give rows {0-3,8-11} (hi=0) / {4-7,12-15} (hi=1).
// Next-layer weights are COLUMN-PERMUTED perm=[0-3,8-11 | 4-7,12-15] so that
// B elem j == relu(cvt(D reg j)) -- layers chain with zero cross-lane ops.
//
// Input layer: B_in = [cvtpk(x.x,x.y),0,0,0] in every lane (each lane's own
// point). Two A_in variants: wi0 (k0,k1=W_in, rest 0) weights only hi=0
// lanes' data -> stream0 (points base+0..31); wi1 (k8,k9=W_in) -> stream1
// (points base+32..63). One shared B serves both input MFMAs.
// Output layer: W_out padded to rows 0,1 -> D rows 0,1 = regs 0,1 @ hi=0;
// lanes 0-31 store float2 results for both streams (offset +32 pts).

typedef _Float16 h8 __attribute__((ext_vector_type(8)));
typedef float f16v __attribute__((ext_vector_type(16)));
typedef float f4 __attribute__((ext_vector_type(4)));
typedef float f2 __attribute__((ext_vector_type(2)));
typedef unsigned int u32;
typedef u32 u4v __attribute__((ext_vector_type(4)));

static __device__ __forceinline__ f16v mfma32(h8 a, h8 b, f16v c) {
    return __builtin_amdgcn_mfma_f32_32x32x16_f16(a, b, c, 0, 0, 0);
}

static __device__ __forceinline__ u32 cvtpk(float a, float b) {
    return __builtin_bit_cast(u32, __builtin_amdgcn_cvt_pkrtz(a, b));
}

static __device__ __forceinline__ h8 pack4(u32 a, u32 b, u32 c, u32 d) {
    u4v p = {a, b, c, d};
    return __builtin_bit_cast(h8, p);
}

// quad-permuted weight fragment: j0-3 = cols 4*hi..4*hi+3, j4-7 = cols 8+4*hi..
static __device__ __forceinline__ h8 wfrag(const float* row, int hi) {
    const f4* r4 = (const f4*)row;
    f4 q0 = r4[hi], q1 = r4[hi + 2];
    return pack4(cvtpk(q0.x, q0.y), cvtpk(q0.z, q0.w),
                 cvtpk(q1.x, q1.y), cvtpk(q1.z, q1.w));
}

// relu + cvt of D regs 0-7 -> next layer's B fragment (order-preserving)
static __device__ __forceinline__ h8 cvt_relu8(f16v a) {
    h8 hb = pack4(cvtpk(a[0], a[1]), cvtpk(a[2], a[3]),
                  cvtpk(a[4], a[5]), cvtpk(a[6], a[7]));
    const h8 z = {};
    return __builtin_elementwise_max(hb, z);   // 4x v_pk_max_f16
}

__global__ __launch_bounds__(256) void denoiser_mfma32(
    const f2* __restrict__ x,        // [N] points (x0,x1)
    const float* __restrict__ w_in,  // [16][2]
    const float* __restrict__ w_mid, // [5][16][16]
    const float* __restrict__ w_out, // [2][16]
    f2* __restrict__ out,            // [N] (o0,o1)
    int n)
{
    const int lane = threadIdx.x & 63;
    const int m    = lane & 15;   // weight row (rows duplicated mod 16)
    const int hi   = lane >> 5;   // half-wave / k-group
    const int wave = threadIdx.x >> 6;

    const f16v z16 = {};
    const h8   hz  = {};

    // ---- one-time weight fragments ----
    u32 wxy = cvtpk(w_in[2 * m], w_in[2 * m + 1]);
    h8 wi0 = hi == 0 ? pack4(wxy, 0u, 0u, 0u) : hz;   // stream0: k0,k1
    h8 wi1 = hi == 1 ? pack4(wxy, 0u, 0u, 0u) : hz;   // stream1: k8,k9

    h8 wm[5];
    #pragma unroll
    for (int l = 0; l < 5; ++l)
        wm[l] = wfrag(w_mid + l * 256 + m * 16, hi);

    h8 wo = m < 2 ? wfrag(w_out + m * 16, hi) : hz;

    const int nchunks = (n + 255) >> 8;     // 256 pts per block-iteration
    for (int c = blockIdx.x; c < nchunks; c += gridDim.x) {
        const int base = c * 256 + wave * 64;   // this wave's 64 points
        const bool full = (base + 64 <= n);     // wave-uniform

        f2 xy;
        if (full) {
            xy = x[base + lane];
        } else {
            int pi = base + lane;
            xy = x[pi < n ? pi : n - 1];
        }

        // ---- input layer: shared B, two half-masked A variants ----
        h8 bin = pack4(cvtpk(xy.x, xy.y), 0u, 0u, 0u);
        f16v a0 = mfma32(wi0, bin, z16);
        f16v a1 = mfma32(wi1, bin, z16);
        h8 b0 = cvt_relu8(a0);
        h8 b1 = cvt_relu8(a1);

        // ---- 5 mid layers (perm-loaded weights -> direct chaining) ----
        #pragma unroll
        for (int l = 0; l < 5; ++l) {
            a0 = mfma32(wm[l], b0, z16);
            a1 = mfma32(wm[l], b1, z16);
            b0 = cvt_relu8(a0);
            b1 = cvt_relu8(a1);
        }

        // ---- output layer: rows 0,1 -> regs 0,1 @ hi=0 ----
        a0 = mfma32(wo, b0, z16);
        a1 = mfma32(wo, b1, z16);

        if (lane < 32) {
            int p0 = base + lane;
            if (full) {
                out[p0]      = (f2){a0[0], a0[1]};
                out[p0 + 32] = (f2){a1[0], a1[1]};
            } else {
                if (p0 < n)      out[p0]      = (f2){a0[0], a0[1]};
                if (p0 + 32 < n) out[p0 + 32] = (f2){a1[0], a1[1]};
            }
        }
    }
}

extern "C" void kernel_launch(void* const* d_in, const int* in_sizes, int n_in,
                              void* d_out, int out_size, void* d_ws, size_t ws_size,
                              hipStream_t stream) {
    const float* x     = (const float*)d_in[0];
    const float* w_in  = (const float*)d_in[1];
    const float* w_mid = (const float*)d_in[2];
    const float* w_out = (const float*)d_in[3];

    int n = in_sizes[0] / 2;          // number of points
    int nchunks = (n + 255) / 256;
    int blocks = nchunks < 2048 ? nchunks : 2048;  // persistent, 8 blocks/CU

    denoiser_mfma32<<<blocks, 256, 0, stream>>>(
        (const f2*)x, w_in, w_mid, w_out, (f2*)d_out, n);
}